// Round 4
// baseline (208.725 us; speedup 1.0000x reference)
//
#include <hip/hip_runtime.h>
#include <stdint.h>

typedef __attribute__((ext_vector_type(4)))  int   intx4;
typedef __attribute__((ext_vector_type(8)))  int   intx8;
typedef __attribute__((ext_vector_type(16))) float floatx16;

#define GLL16(gp, lp)                                                               \
    __builtin_amdgcn_global_load_lds((const __attribute__((address_space(1))) unsigned int*)(gp), \
                                     (__attribute__((address_space(3))) unsigned int*)(lp), 16, 0, 0)
#define GLL4(gp, lp)                                                                \
    __builtin_amdgcn_global_load_lds((const __attribute__((address_space(1))) unsigned int*)(gp), \
                                     (__attribute__((address_space(3))) unsigned int*)(lp), 4, 0, 0)

// ---------------------------------------------------------------------------
// Kernel 1: quantize x -> packed e2m1 nibbles + e8m0 codes (natural [m][kb]).
// Thread = 8 consecutive floats; 4 consecutive lanes = one 32-elem MX block.
// ---------------------------------------------------------------------------
__device__ __forceinline__ uint32_t enc1(float xv, float inv) {
    float a = fminf(fabsf(xv) * inv, 6.0f);
    // RTE onto e2m1 grid {0,.5,1,1.5,2,3,4,6} -> code 0..7 (ties-to-even == ref)
    int e;
    if (a < 2.0f)      e = (int)rintf(a + a);
    else if (a < 4.0f) e = (int)rintf(a) + 2;
    else               e = (int)rintf(a * 0.5f) + 4;
    return (uint32_t)e | ((__float_as_uint(xv) >> 28) & 8u);
}

__global__ __launch_bounds__(256) void quant_x_kernel(const float* __restrict__ x,
                                                      uint32_t* __restrict__ xq,
                                                      uint8_t* __restrict__ xs) {
    int t = blockIdx.x * 256 + threadIdx.x;          // 8-float group index
    const float4* src = (const float4*)(x + (size_t)t * 8);
    float4 v0 = src[0], v1 = src[1];
    float mx = fmaxf(fmaxf(fmaxf(fabsf(v0.x), fabsf(v0.y)), fmaxf(fabsf(v0.z), fabsf(v0.w))),
                     fmaxf(fmaxf(fabsf(v1.x), fabsf(v1.y)), fmaxf(fabsf(v1.z), fabsf(v1.w))));
    // max over 4-lane subgroup = one MX block
    mx = fmaxf(mx, __shfl_xor(mx, 1, 64));
    mx = fmaxf(mx, __shfl_xor(mx, 2, 64));
    // FLOOR e8m0 code = exp_field - 2, clamped >= 1 (scale >= 2^-126, ref clamp)
    unsigned ef = __float_as_uint(mx) >> 23;
    unsigned code = (ef < 3u) ? 1u : (ef - 2u);
    float inv = __uint_as_float((254u - code) << 23);   // exact 2^(127-code)

    uint32_t w =  enc1(v0.x, inv)        | (enc1(v0.y, inv) << 4)
               | (enc1(v0.z, inv) << 8)  | (enc1(v0.w, inv) << 12)
               | (enc1(v1.x, inv) << 16) | (enc1(v1.y, inv) << 20)
               | (enc1(v1.z, inv) << 24) | (enc1(v1.w, inv) << 28);
    xq[t] = w;
    if ((threadIdx.x & 3) == 0) xs[t >> 2] = (uint8_t)code;   // natural [m][kb], coalesced
}

// ---------------------------------------------------------------------------
// Kernel 2: densify. setup stores one byte per int32 for both weight_packed
// and weight_scale. wrep[i]=(u8)wp[i]; wscb[i]=(u8)wsc[i]. 4 ints -> 1 word.
// ---------------------------------------------------------------------------
__global__ __launch_bounds__(256) void repack_kernel(const int* __restrict__ wp,
                                                     const int* __restrict__ wsc,
                                                     uint32_t* __restrict__ wrep,
                                                     uint32_t* __restrict__ wscb,
                                                     int n4w, int n4s) {
    int t = blockIdx.x * 256 + threadIdx.x;
    if (t < n4w) {
        int4 p = ((const int4*)wp)[t];
        wrep[t] = (uint32_t)(p.x & 0xFF) | ((uint32_t)(p.y & 0xFF) << 8)
                | ((uint32_t)(p.z & 0xFF) << 16) | ((uint32_t)(p.w & 0xFF) << 24);
    } else if (t - n4w < n4s) {
        int u = t - n4w;
        int4 p = ((const int4*)wsc)[u];
        wscb[u] = (uint32_t)(p.x & 0xFF) | ((uint32_t)(p.y & 0xFF) << 8)
                | ((uint32_t)(p.z & 0xFF) << 16) | ((uint32_t)(p.w & 0xFF) << 24);
    }
}

// ---------------------------------------------------------------------------
// Kernel 3: MXFP4 GEMM, 256x256 block tile, 4 waves (2x2) each 128x128 via
// 4x4 v_mfma_scale_f32_32x32x64_f8f6f4 (fmt 4 = fp4). BK=128 (64 B/row),
// double-buffered LDS, GLL staging. Swizzle slot(r,p)=4r+(p^((r>>1)&3)) makes
// slot%8 bijective over 8 consecutive rows -> conflict-free ds_read_b128.
// Scales gathered per-row via GLL4 from natural [row][kb] layout.
// ---------------------------------------------------------------------------
__global__ __launch_bounds__(256, 1) void gemm_mx_kernel(const uint8_t* __restrict__ Apk,
                                                         const uint8_t* __restrict__ Bpk,
                                                         const uint8_t* __restrict__ As,
                                                         const uint8_t* __restrict__ Bs,
                                                         float* __restrict__ C,
                                                         int M, int N, int K) {
    __shared__ __align__(16) uint8_t sA[2][16384];    // 256 rows x 64 B
    __shared__ __align__(16) uint8_t sB[2][16384];
    __shared__ __align__(16) uint8_t sAs[2][1024];    // [row][kb 0..3]
    __shared__ __align__(16) uint8_t sBs[2][1024];

    const int tid = threadIdx.x;
    const int bm0 = blockIdx.y << 8;
    const int bn0 = blockIdx.x << 8;
    const int wave = tid >> 6;
    const int lane = tid & 63;
    const int wm = (wave >> 1) << 7;                  // 0 or 128
    const int wn = (wave & 1) << 7;
    const int row = lane & 31;
    const int h = lane >> 5;
    const int Kb = K >> 1;                            // 2048 packed bytes/row
    const int kbpr = K >> 5;                          // 128 scale bytes/row

    // staging slots: i=0..3, slot = tid + 256*i
    int soff[4];                                      // LDS byte offset = slot*16
    const uint8_t* Aga[4];
    const uint8_t* Bga[4];
#pragma unroll
    for (int i = 0; i < 4; ++i) {
        int s = tid + 256 * i;
        int r = s >> 2;
        int p = (s & 3) ^ ((r >> 1) & 3);
        soff[i] = s * 16;
        Aga[i] = Apk + (size_t)(bm0 + r) * Kb + p * 16;
        Bga[i] = Bpk + (size_t)(bn0 + r) * Kb + p * 16;
    }
    const uint8_t* Asg = As + (size_t)(bm0 + tid) * kbpr;   // 4 B/chunk, per-lane gather
    const uint8_t* Bsg = Bs + (size_t)(bn0 + tid) * kbpr;

    floatx16 acc[4][4];
#pragma unroll
    for (int a = 0; a < 4; ++a)
#pragma unroll
        for (int b = 0; b < 4; ++b)
#pragma unroll
            for (int r = 0; r < 16; ++r) acc[a][b][r] = 0.f;

    const int nchunk = K >> 7;                        // 32

    // prologue: stage chunk 0 into buffer 0
#pragma unroll
    for (int i = 0; i < 4; ++i) {
        GLL16(Aga[i], sA[0] + soff[i]);
        GLL16(Bga[i], sB[0] + soff[i]);
    }
    GLL4(Asg, sAs[0] + tid * 4);
    GLL4(Bsg, sBs[0] + tid * 4);

    for (int c = 0; c < nchunk; ++c) {
        const int buf = c & 1;
        __syncthreads();                              // drains stage(c); frees buf^1
        if (c + 1 < nchunk) {
            const int nb = buf ^ 1;
            const size_t koff = (size_t)(c + 1) * 64;
#pragma unroll
            for (int i = 0; i < 4; ++i) {
                GLL16(Aga[i] + koff, sA[nb] + soff[i]);
                GLL16(Bga[i] + koff, sB[nb] + soff[i]);
            }
            GLL4(Asg + (c + 1) * 4, sAs[nb] + tid * 4);
            GLL4(Bsg + (c + 1) * 4, sBs[nb] + tid * 4);
        }

#pragma unroll
        for (int s = 0; s < 2; ++s) {
            const int kp = 2 * s + h;                 // 16-B piece = one MX block
            intx4 a4[4], b4[4];
            int sa[4], sb[4];
#pragma unroll
            for (int mt = 0; mt < 4; ++mt) {
                const int lr = wm + mt * 32 + row;
                a4[mt] = *(const intx4*)(sA[buf] + (lr * 4 + (kp ^ ((lr >> 1) & 3))) * 16);
                sa[mt] = sAs[buf][lr * 4 + kp];
            }
#pragma unroll
            for (int nt = 0; nt < 4; ++nt) {
                const int lr = wn + nt * 32 + row;
                b4[nt] = *(const intx4*)(sB[buf] + (lr * 4 + (kp ^ ((lr >> 1) & 3))) * 16);
                sb[nt] = sBs[buf][lr * 4 + kp];
            }
#pragma unroll
            for (int mt = 0; mt < 4; ++mt)
#pragma unroll
                for (int nt = 0; nt < 4; ++nt) {
                    intx8 a8 = {a4[mt][0], a4[mt][1], a4[mt][2], a4[mt][3], 0, 0, 0, 0};
                    intx8 b8 = {b4[nt][0], b4[nt][1], b4[nt][2], b4[nt][3], 0, 0, 0, 0};
                    acc[mt][nt] = __builtin_amdgcn_mfma_scale_f32_32x32x64_f8f6f4(
                        a8, b8, acc[mt][nt], 4, 4, 0, sa[mt], 0, sb[nt]);
                }
        }
    }

    // C/D layout (32x32): col = lane&31, row = (reg&3) + 8*(reg>>2) + 4*(lane>>5)
#pragma unroll
    for (int mt = 0; mt < 4; ++mt)
#pragma unroll
        for (int nt = 0; nt < 4; ++nt) {
            const int col = bn0 + wn + nt * 32 + row;
#pragma unroll
            for (int g = 0; g < 4; ++g) {
                const int rw = bm0 + wm + mt * 32 + 8 * g + 4 * h;
#pragma unroll
                for (int q = 0; q < 4; ++q)
                    C[(size_t)(rw + q) * N + col] = acc[mt][nt][4 * g + q];
            }
        }
}

// ---------------------------------------------------------------------------
extern "C" void kernel_launch(void* const* d_in, const int* in_sizes, int n_in,
                              void* d_out, int out_size, void* d_ws, size_t ws_size,
                              hipStream_t stream) {
    const float* x = (const float*)d_in[0];
    const int* wp = (const int*)d_in[1];
    const int* wsc = (const int*)d_in[2];
    float* out = (float*)d_out;

    const int K = 4096;
    const int M = in_sizes[0] / K;            // 4096
    const int N = (in_sizes[1] * 2) / K;      // 4096
    const int kbpr = K / 32;                  // 128
    const int npack = N * K / 2;
    const int nsc = N * kbpr;

    uint32_t* xq   = (uint32_t*)d_ws;                                   // 8 MiB
    uint8_t*  xs   = (uint8_t*)d_ws + (size_t)M * K / 2;                // 512 KiB
    uint32_t* wrep = (uint32_t*)(xs + (size_t)M * kbpr);                // 8 MiB
    uint8_t*  wscb = (uint8_t*)wrep + (size_t)npack;                    // 512 KiB

    quant_x_kernel<<<(M * K / 8) / 256, 256, 0, stream>>>(x, xq, xs);

    int n4w = npack / 4, n4s = nsc / 4;
    repack_kernel<<<(n4w + n4s + 255) / 256, 256, 0, stream>>>(wp, wsc, wrep,
                                                               (uint32_t*)wscb, n4w, n4s);

    dim3 grid(N / 256, M / 256);
    gemm_mx_kernel<<<grid, 256, 0, stream>>>((const uint8_t*)xq, (const uint8_t*)wrep,
                                             xs, wscb, out, M, N, K);
}